// Round 6
// baseline (267.137 us; speedup 1.0000x reference)
//
#include <hip/hip_runtime.h>
#include <hip/hip_bf16.h>

typedef __bf16 bf16x8 __attribute__((ext_vector_type(8)));
typedef __bf16 bf16x4 __attribute__((ext_vector_type(4)));
typedef float f32x4 __attribute__((ext_vector_type(4)));
typedef float f32x16 __attribute__((ext_vector_type(16)));

#define NTOK 16384
#define DIN  256
#define DHID 512
#define DOUT 256
#define NEXP 8
#define MAXB 516  // ceil((2 * (16384/32 + 7)) / 4) waves -> blocks of 4 waves

#define MFMA32(a, b, c) __builtin_amdgcn_mfma_f32_32x32x16_bf16(a, b, c, 0, 0, 0)

// ---------------------------------------------------------------------------
// Fused prep: b<512 -> gate (+x->bf16); b<1024 -> W1 retile; else W2 retile.
// Both retiles write COALESCED (linear fi), reads coalesced per-j.
//
// W1 retile  [e][hc:8][rt:2][kw:16][lane:64][j:8]:
//   val = W1[e][k = kw*16+(lane>>5)*8+j][hid = hc*64+rt*32+(lane&31)]
// W2 retile  [e][hc:8][oh:2][ot:4][kw:4][lane:64][j:8]:
//   val = W2[e][hid = hc*64+kw*16+(lane>>5)*8+j][out = oh*128+ot*32+(lane&31)]
__global__ __launch_bounds__(256) void prep_kernel(
    const float* __restrict__ x, const float* __restrict__ wg,
    const float* __restrict__ w1, const float* __restrict__ w2,
    int* __restrict__ cnt, int* __restrict__ btok, float* __restrict__ bw,
    __bf16* __restrict__ xbf, __bf16* __restrict__ w1bf,
    __bf16* __restrict__ w2bf) {
  __shared__ int lcnt[NEXP];
  __shared__ int lbase[NEXP];
  const int b = blockIdx.x;
  const int tid = threadIdx.x;

  if (b >= 512) {
    if (b < 1024) {  // W1 retile
      int e = (b - 512) >> 6;
      int fi = ((b - 512) & 63) * 256 + tid;  // [0, 16384)
      int lane = fi & 63;
      int kw = (fi >> 6) & 15;
      int rt = (fi >> 10) & 1;
      int hc = (fi >> 11) & 7;
      int k0 = kw * 16 + (lane >> 5) * 8;
      int hid = hc * 64 + rt * 32 + (lane & 31);
      const float* s = w1 + ((size_t)e * 256 + k0) * 512 + hid;
      bf16x8 t;
#pragma unroll
      for (int j = 0; j < 8; ++j) t[j] = (__bf16)s[(size_t)j * 512];
      *(bf16x8*)(w1bf + (size_t)e * 131072 + (size_t)fi * 8) = t;
    } else {         // W2 retile
      int e = (b - 1024) >> 6;
      int fi = ((b - 1024) & 63) * 256 + tid;  // [0, 16384)
      int lane = fi & 63;
      int kw = (fi >> 6) & 3;
      int ot = (fi >> 8) & 3;
      int oh = (fi >> 10) & 1;
      int hc = (fi >> 11) & 7;
      int hid0 = hc * 64 + kw * 16 + (lane >> 5) * 8;
      int o = oh * 128 + ot * 32 + (lane & 31);
      const float* s = w2 + ((size_t)e * 512 + hid0) * 256 + o;
      bf16x8 t;
#pragma unroll
      for (int j = 0; j < 8; ++j) t[j] = (__bf16)s[(size_t)j * 256];
      *(bf16x8*)(w2bf + (size_t)e * 131072 + (size_t)fi * 8) = t;
    }
    return;
  }

  // ---- gate part: 8 lanes/token, 32 tokens/block ----
  if (tid < NEXP) lcnt[tid] = 0;

  const int sub = tid & 7;
  const int tslot = tid >> 3;
  const int token = b * 32 + tslot;
  const f32x4* xr = (const f32x4*)(x + (size_t)token * DIN + sub * 32);
  const float* wr0 = wg + (size_t)sub * 32 * NEXP;

  bf16x8 xb[4];
  f32x4 p0 = {0.f, 0.f, 0.f, 0.f}, p1 = {0.f, 0.f, 0.f, 0.f};
#pragma unroll
  for (int j4 = 0; j4 < 8; ++j4) {
    f32x4 xv = xr[j4];
    const float* wr = wr0 + j4 * 32;
#pragma unroll
    for (int d = 0; d < 4; ++d) {
      float xs_ = xv[d];
      p0 += xs_ * *(const f32x4*)(wr + 8 * d);
      p1 += xs_ * *(const f32x4*)(wr + 8 * d + 4);
      xb[j4 >> 1][(j4 & 1) * 4 + d] = (__bf16)xs_;
    }
  }
  {
    bf16x8* xdst = (bf16x8*)(xbf + (size_t)token * DIN + sub * 32);
#pragma unroll
    for (int i = 0; i < 4; ++i) xdst[i] = xb[i];
  }

  double acc[NEXP];
#pragma unroll
  for (int d = 0; d < 4; ++d) {
    acc[d] = (double)p0[d];
    acc[4 + d] = (double)p1[d];
  }
#pragma unroll
  for (int off = 1; off < 8; off <<= 1)
#pragma unroll
    for (int e = 0; e < NEXP; ++e) acc[e] += __shfl_xor(acc[e], off, 64);

  __syncthreads();  // lcnt zeroing visible

  int i1 = 0, i2 = 0, o1 = 0, o2 = 0;
  float w1s = 0.f, w2s = 0.f;
  if (sub == 0) {
    double bv1 = acc[0];
#pragma unroll
    for (int e = 1; e < NEXP; ++e)
      if (acc[e] > bv1) { bv1 = acc[e]; i1 = e; }
    double bv2 = -1e300;
#pragma unroll
    for (int e = 0; e < NEXP; ++e)
      if (e != i1 && acc[e] > bv2) { bv2 = acc[e]; i2 = e; }
    float dd = expf((float)(bv2 - bv1));
    w1s = 1.0f / (1.0f + dd);
    w2s = dd * w1s;
    o1 = atomicAdd(&lcnt[i1], 1);
    o2 = atomicAdd(&lcnt[i2], 1);
  }
  __syncthreads();
  if (tid < NEXP) lbase[tid] = atomicAdd(&cnt[tid], lcnt[tid]);
  __syncthreads();
  if (sub == 0) {
    int s1 = lbase[i1] + o1, s2 = lbase[i2] + o2;
    btok[i1 * NTOK + s1] = token;           // slot 0
    bw[i1 * NTOK + s1] = w1s;
    btok[i2 * NTOK + s2] = token | 16384;   // slot 1 (bit 14)
    bw[i2 * NTOK + s2] = w2s;
  }
}

// ---------------------------------------------------------------------------
// Expert FFN, round 12: WAVE-INDEPENDENT. R2(2 blk/CU) == R5(1 blk/CU) ==
// 52.5us proved the barrier-convoy structure is the limiter, not residency
// or chunk count. Here each wave owns (32 tokens x 128 out cols) with NO
// __syncthreads in the main loop:
//  - W1/W2 fragments stream from prep-retiled contiguous layouts (1KB bursts,
//    L2-served, shared read-only across all waves of the same expert).
//  - phase A (K=256) -> S in C-layout -> relu+bias -> 4KB wave-PRIVATE LDS
//    scratch (parity double-buffered, verified hs swizzle) -> phase B B-frags.
//    Ordering needs only lgkmcnt(0), no barrier.
//  - 2062 free-running waves (8/CU) latency-hide each other.
// Cost: phase A duplicated x2 (out-half split) -> MFMA floor 10.4us.
__global__ __launch_bounds__(256, 2) void ffn_kernel(
    const __bf16* __restrict__ xbf, const __bf16* __restrict__ w1bf,
    const __bf16* __restrict__ w2bf, const float* __restrict__ b1g,
    const float* __restrict__ b2g, const int* __restrict__ cnt,
    const int* __restrict__ btok, const float* __restrict__ bw,
    __bf16* __restrict__ pout) {
  __shared__ __align__(16) __bf16 hscr[4][2][32 * 64];  // per-wave 2x4KB

  const int tid = threadIdx.x;
  const int lane = tid & 63;
  const int wid = tid >> 6;
  const int l31 = lane & 31;
  const int hi = lane >> 5;

  const int W = blockIdx.x * 4 + wid;  // global wave id
  const int T = W >> 1;                // 32-token tile id
  const int oh = W & 1;                // out-half

  int e = -1, start = 0;
  {
    int a0 = 0;
#pragma unroll
    for (int q = 0; q < NEXP; ++q) {
      int t = (cnt[q] + 31) >> 5;
      if (e < 0 && T < a0 + t) { e = q; start = (T - a0) * 32; }
      a0 += t;
    }
  }
  if (e < 0) return;
  const int ce = cnt[e];

  // per-lane routing (this lane's token column = l31)
  const int idx = start + l31;
  const bool v = idx < ce;
  const int entry = v ? btok[e * NTOK + idx] : 0;
  const int mytok = entry & 16383;
  const int msrow = (entry >> 14) * NTOK + mytok;
  const float mwgt = v ? bw[e * NTOK + idx] : 0.0f;

  // x as phase-A B-operand: lane holds B[k-slice][col=l31]
  bf16x8 xB[16];
  {
    const __bf16* xr = xbf + (size_t)mytok * DIN + hi * 8;
#pragma unroll
    for (int kw = 0; kw < 16; ++kw) xB[kw] = *(const bf16x8*)(xr + kw * 16);
  }

  const __bf16* w1e = w1bf + (size_t)e * 131072;
  const __bf16* w2e = w2bf + (size_t)e * 131072;
  const float* b1e = b1g + e * DHID;
  const float* b2e = b2g + e * DOUT;

  f32x16 acc[4];
#pragma unroll
  for (int ot = 0; ot < 4; ++ot)
#pragma unroll
    for (int r = 0; r < 16; ++r) acc[ot][r] = 0.f;

  const int rot = (W >> 3) & 7;  // co-resident-block L1 affinity; L2 spread

#pragma unroll
  for (int hc0 = 0; hc0 < 8; ++hc0) {
    const int hc = (hc0 + rot) & 7;
    __bf16* hb = &hscr[wid][hc0 & 1][0];

    // ---- phase A: S[64 hid x 32 tok] = W1c x x, K=256 (2 row-tiles)
    const __bf16* w1c = w1e + (size_t)hc * 16384;
#pragma unroll
    for (int rt = 0; rt < 2; ++rt) {
      f32x16 Sp[2];
#pragma unroll
      for (int r = 0; r < 16; ++r) { Sp[0][r] = 0.f; Sp[1][r] = 0.f; }
#pragma unroll
      for (int kw = 0; kw < 16; ++kw) {
        bf16x8 a = *(const bf16x8*)(w1c + (size_t)((rt * 16 + kw) * 64 + lane) * 8);
        Sp[kw & 1] = MFMA32(a, xB[kw], Sp[kw & 1]);
      }
      f32x16 S = Sp[0] + Sp[1];
      // bias + relu -> wave-private scratch (verified hs swizzle, m = l31)
#pragma unroll
      for (int g = 0; g < 4; ++g) {
        int hl = rt * 32 + 8 * g + 4 * hi;
        f32x4 bv = *(const f32x4*)(b1e + hc * 64 + hl);
        bf16x4 pk;
#pragma unroll
        for (int r = 0; r < 4; ++r)
          pk[r] = (__bf16)fmaxf(S[4 * g + r] + bv[r], 0.f);
        int slt = (hl >> 3) ^ (l31 & 7);
        *(bf16x4*)((char*)hb + l31 * 128 + slt * 16 + (hl & 7) * 2) = pk;
      }
    }
    asm volatile("s_waitcnt lgkmcnt(0)" ::: "memory");  // scratch writes done
    __builtin_amdgcn_sched_barrier(0);

    // ---- phase B: acc[128 out x 32 tok] += W2c(oh) x h, K=64
    const __bf16* w2c = w2e + (size_t)hc * 16384 + (size_t)oh * 8192;
#pragma unroll
    for (int kw = 0; kw < 4; ++kw) {
      int s = (kw * 2 + hi) ^ (l31 & 7);
      bf16x8 hf = *(const bf16x8*)((const char*)hb + l31 * 128 + s * 16);
#pragma unroll
      for (int ot = 0; ot < 4; ++ot) {
        bf16x8 wf = *(const bf16x8*)(w2c + (size_t)((ot * 4 + kw) * 64 + lane) * 8);
        acc[ot] = MFMA32(wf, hf, acc[ot]);
      }
    }
  }

  // ---- epilogue: pout[msrow][oc] = bf16(w * (acc + b2)), this lane's token
  if (v) {
    __bf16* prow = pout + (size_t)msrow * DOUT;
#pragma unroll
    for (int ot = 0; ot < 4; ++ot) {
#pragma unroll
      for (int g = 0; g < 4; ++g) {
        int o0 = oh * 128 + ot * 32 + 8 * g + 4 * hi;
        f32x4 bv = *(const f32x4*)(b2e + o0);
        bf16x4 pk;
#pragma unroll
        for (int r = 0; r < 4; ++r)
          pk[r] = (__bf16)(mwgt * (acc[ot][4 * g + r] + bv[r]));
        *(bf16x4*)(prow + o0) = pk;
      }
    }
  }
}

// ---------------------------------------------------------------------------
// out[t][c] = pout[0][t][c] + pout[1][t][c]   (streaming, 8 elems/thread)
__global__ __launch_bounds__(256) void combine_kernel(const __bf16* __restrict__ pout,
                                                      float* __restrict__ out) {
  int f = blockIdx.x * 256 + threadIdx.x;  // [0, NTOK*DOUT/8)
  bf16x8 a = *(const bf16x8*)(pout + (size_t)f * 8);
  bf16x8 b = *(const bf16x8*)(pout + (size_t)NTOK * DOUT + (size_t)f * 8);
  float4 o0, o1;
  o0.x = (float)a[0] + (float)b[0];
  o0.y = (float)a[1] + (float)b[1];
  o0.z = (float)a[2] + (float)b[2];
  o0.w = (float)a[3] + (float)b[3];
  o1.x = (float)a[4] + (float)b[4];
  o1.y = (float)a[5] + (float)b[5];
  o1.z = (float)a[6] + (float)b[6];
  o1.w = (float)a[7] + (float)b[7];
  float4* dst = (float4*)(out + (size_t)f * 8);
  dst[0] = o0;
  dst[1] = o1;
}

// ---------------------------------------------------------------------------
extern "C" void kernel_launch(void* const* d_in, const int* in_sizes, int n_in,
                              void* d_out, int out_size, void* d_ws, size_t ws_size,
                              hipStream_t stream) {
  const float* x = (const float*)d_in[0];
  const float* Wg = (const float*)d_in[1];
  const float* W1 = (const float*)d_in[2];
  const float* b1 = (const float*)d_in[3];
  const float* W2 = (const float*)d_in[4];
  const float* b2 = (const float*)d_in[5];
  float* out = (float*)d_out;

  char* ws = (char*)d_ws;
  int* cnt = (int*)(ws + 0);                    //      32 B
  int* btok = (int*)(ws + 256);                 //  512 KiB
  float* bw = (float*)(ws + 524544);            //  512 KiB
  __bf16* xbf = (__bf16*)(ws + 1048832);        //    8 MiB
  __bf16* w1bf = (__bf16*)(ws + 9437440);       //    2 MiB
  __bf16* w2bf = (__bf16*)(ws + 11534592);      //    2 MiB
  __bf16* pout = (__bf16*)(ws + 13631744);      //   16 MiB (end ~29 MiB)

  hipMemsetAsync(cnt, 0, NEXP * sizeof(int), stream);

  prep_kernel<<<dim3(1536), dim3(256), 0, stream>>>(x, Wg, W1, W2, cnt, btok,
                                                    bw, xbf, w1bf, w2bf);
  ffn_kernel<<<dim3(MAXB), dim3(256), 0, stream>>>(xbf, w1bf, w2bf, b1, b2,
                                                   cnt, btok, bw, pout);
  combine_kernel<<<dim3(NTOK * DOUT / 8 / 256), dim3(256), 0, stream>>>(pout, out);
}